// Round 10
// baseline (118.608 us; speedup 1.0000x reference)
//
#include <hip/hip_runtime.h>
#include <hip/hip_bf16.h>

// Problem constants
#define D_DIM 512
#define K_DIM 512
#define B_C   64

// Tile config: 128x256 tile (halves W redundancy vs 128x128), 4 waves (2x2,
// each 64r x 128c), BK=64, single-buffered LDS 48 KiB, fused transient staging.
#define BM 128
#define BN 256
#define BK 64
#define KSTEPS 8             // D_DIM / BK
#define ROWT 8               // LMAX / BM
#define COLT 2               // K_DIM / BN
#define NWG  (B_C * ROWT * COLT)   // 1024, divisible by 8 XCDs

typedef __attribute__((ext_vector_type(8))) short bf16x8;
typedef __attribute__((ext_vector_type(4))) float f32x4;

__device__ __forceinline__ short f2bf(float f) {
    union { __hip_bfloat16 h; short s; } u;
    u.h = __float2bfloat16(f);
    return u.s;
}

// R3-validated zero-conflict swizzle for 128B rows (8 x 16B slots):
// slot' = slot ^ ((r&7) ^ ((r>>2)&7))
__device__ __forceinline__ int fS(int r) { return (r & 7) ^ ((r >> 2) & 7); }

__global__ __launch_bounds__(256, 2) void jbmm_kernel(
    const int* __restrict__ offsets,   // B+1
    const int* __restrict__ index,     // B
    const float* __restrict__ jagged,  // T x D
    const float* __restrict__ weight,  // NW x D x K
    const float* __restrict__ bias,    // NW x K
    float* __restrict__ out)           // T x K
{
    __shared__ short As[BM * BK];      // 16 KB, row stride 128 B
    __shared__ short Bs[BN * BK];      // 32 KB, row stride 128 B (transposed W)

    // XCD chunk swizzle (1024 % 8 == 0 -> bijective)
    const int bidRaw = blockIdx.x;
    const int bid = (bidRaw & 7) * (NWG / 8) + (bidRaw >> 3);

    const int b   = bid / (ROWT * COLT);
    const int rt  = (bid / COLT) % ROWT;
    const int ct  = bid % COLT;

    const int start = offsets[b];
    const int end   = offsets[b + 1];
    const int m0    = start + rt * BM;
    if (m0 >= end) return;
    const int rows = (end - m0) < BM ? (end - m0) : BM;

    const int idxw = index[b];
    const float* W = weight + (size_t)idxw * D_DIM * K_DIM;
    const int n0 = ct * BN;

    const int tid  = threadIdx.x;
    const int lane = tid & 63;
    const int wid  = tid >> 6;
    const int wr   = wid >> 1;   // 0..1: rows wr*64..+63
    const int wc   = wid & 1;    // 0..1: cols wc*128..+127
    const int lr   = lane & 15;
    const int lg   = lane >> 4;

    // staging maps
    const int arow  = tid >> 3;  // 0..31 (+32*i): A row
    const int acol8 = tid & 7;   // 0..7: 8 consecutive f32 at k = acol8*8
    const int nq    = tid & 63;  // 0..63: B n-quad (rows 4*nq..+3)
    const int kg    = tid >> 6;  // 0..3: k-group of 16 (two 8-slots)

    float bias_v[8];
#pragma unroll
    for (int ni = 0; ni < 8; ++ni)
        bias_v[ni] = bias[(size_t)idxw * K_DIM + n0 + wc * 128 + ni * 16 + lr];

    f32x4 acc[4][8];
#pragma unroll
    for (int mi = 0; mi < 4; ++mi)
#pragma unroll
        for (int ni = 0; ni < 8; ++ni)
            acc[mi][ni] = (f32x4){0.f, 0.f, 0.f, 0.f};

// Fused staging: global load -> cvt -> ds_write, transient registers only.
#define STAGE(k0_)                                                          \
    {                                                                       \
        /* ---- A: 4 rows/thread, 32B each ---- */                          \
        _Pragma("unroll")                                                   \
        for (int i = 0; i < 4; ++i) {                                       \
            const int r = arow + 32 * i;                                    \
            f32x4 v0 = (f32x4){0.f,0.f,0.f,0.f};                            \
            f32x4 v1 = (f32x4){0.f,0.f,0.f,0.f};                            \
            if (r < rows) {                                                 \
                const float* p = &jagged[(size_t)(m0 + r) * D_DIM + (k0_) + acol8 * 8]; \
                v0 = *reinterpret_cast<const f32x4*>(p);                    \
                v1 = *reinterpret_cast<const f32x4*>(p + 4);                \
            }                                                               \
            bf16x8 w8;                                                      \
            w8[0] = f2bf(v0[0]); w8[1] = f2bf(v0[1]);                       \
            w8[2] = f2bf(v0[2]); w8[3] = f2bf(v0[3]);                       \
            w8[4] = f2bf(v1[0]); w8[5] = f2bf(v1[1]);                       \
            w8[6] = f2bf(v1[2]); w8[7] = f2bf(v1[3]);                       \
            *reinterpret_cast<bf16x8*>(                                     \
                (char*)As + r * 128 + ((acol8 ^ fS(r)) << 4)) = w8;         \
        }                                                                   \
        /* ---- B: thread covers 4 n x 16 k, in two 8-k halves ---- */      \
        _Pragma("unroll")                                                   \
        for (int h = 0; h < 2; ++h) {                                       \
            f32x4 bv[8];                                                    \
            _Pragma("unroll")                                               \
            for (int j = 0; j < 8; ++j)                                     \
                bv[j] = *reinterpret_cast<const f32x4*>(                    \
                    &W[(size_t)((k0_) + kg * 16 + h * 8 + j) * K_DIM + n0 + nq * 4]); \
            _Pragma("unroll")                                               \
            for (int np = 0; np < 4; ++np) {                                \
                const int row = nq * 4 + np;                                \
                bf16x8 w8;                                                  \
                w8[0] = f2bf(bv[0][np]); w8[1] = f2bf(bv[1][np]);           \
                w8[2] = f2bf(bv[2][np]); w8[3] = f2bf(bv[3][np]);           \
                w8[4] = f2bf(bv[4][np]); w8[5] = f2bf(bv[5][np]);           \
                w8[6] = f2bf(bv[6][np]); w8[7] = f2bf(bv[7][np]);           \
                *reinterpret_cast<bf16x8*>(                                 \
                    (char*)Bs + row * 128 + (((kg * 2 + h) ^ fS(row)) << 4)) = w8; \
            }                                                               \
        }                                                                   \
    }

#define COMPUTE()                                                           \
    {                                                                       \
        __builtin_amdgcn_s_setprio(1);                                      \
        _Pragma("unroll")                                                   \
        for (int kh = 0; kh < 2; ++kh) {                                    \
            bf16x8 af[4];                                                   \
            _Pragma("unroll")                                               \
            for (int mi = 0; mi < 4; ++mi) {                                \
                const int row = wr * 64 + mi * 16 + lr;                     \
                af[mi] = *reinterpret_cast<bf16x8*>(                        \
                    (char*)As + row * 128 + (((kh * 4 + lg) ^ fS(row)) << 4)); \
            }                                                               \
            _Pragma("unroll")                                               \
            for (int ni = 0; ni < 8; ++ni) {                                \
                const int row = wc * 128 + ni * 16 + lr;                    \
                bf16x8 bfr = *reinterpret_cast<bf16x8*>(                    \
                    (char*)Bs + row * 128 + (((kh * 4 + lg) ^ fS(row)) << 4)); \
                _Pragma("unroll")                                           \
                for (int mi = 0; mi < 4; ++mi)                              \
                    acc[mi][ni] = __builtin_amdgcn_mfma_f32_16x16x32_bf16(  \
                        af[mi], bfr, acc[mi][ni], 0, 0, 0);                 \
            }                                                               \
        }                                                                   \
        __builtin_amdgcn_s_setprio(0);                                      \
    }

// Raw barrier: only LDS ops must drain; global loads stay in flight.
#define BARRIER_LDS()                                                       \
    {                                                                       \
        asm volatile("s_waitcnt lgkmcnt(0)" ::: "memory");                  \
        __builtin_amdgcn_s_barrier();                                       \
        asm volatile("" ::: "memory");                                      \
    }

    // ---- main: single buffer, 2 barriers/step; the 2 resident blocks
    //      anti-phase (one in STAGE/TCP while the other is in COMPUTE/LDS) ----
    STAGE(0);
    BARRIER_LDS();
#pragma unroll
    for (int t = 0; t < KSTEPS; ++t) {
        COMPUTE();
        if (t + 1 < KSTEPS) {
            BARRIER_LDS();             // all waves done reading buffer
            STAGE((t + 1) * BK);
            BARRIER_LDS();             // writes visible
        }
    }

    // ---- epilogue: C/D layout col=lane&15, row=(lane>>4)*4+r ----
#pragma unroll
    for (int mi = 0; mi < 4; ++mi) {
        const int rbase = wr * 64 + mi * 16 + lg * 4;
#pragma unroll
        for (int r = 0; r < 4; ++r) {
            const int rr = rbase + r;
            if (rr < rows) {
#pragma unroll
                for (int ni = 0; ni < 8; ++ni) {
                    out[(size_t)(m0 + rr) * K_DIM + n0 + wc * 128 + ni * 16 + lr] =
                        acc[mi][ni][r] + bias_v[ni];
                }
            }
        }
    }
}

extern "C" void kernel_launch(void* const* d_in, const int* in_sizes, int n_in,
                              void* d_out, int out_size, void* d_ws, size_t ws_size,
                              hipStream_t stream) {
    const int*   offsets = (const int*)d_in[1];
    const int*   index   = (const int*)d_in[2];
    const float* jagged  = (const float*)d_in[3];
    const float* weight  = (const float*)d_in[4];
    const float* bias    = (const float*)d_in[5];
    float*       out     = (float*)d_out;

    dim3 grid(NWG);
    dim3 block(256);
    hipLaunchKernelGGL(jbmm_kernel, grid, block, 0, stream,
                       offsets, index, jagged, weight, bias, out);
}

// Round 11
// 59.393 us; speedup vs baseline: 1.9970x; 1.9970x over previous
//
#include <hip/hip_runtime.h>
#include <hip/hip_bf16.h>

// Problem constants
#define D_DIM 512
#define K_DIM 512
#define B_C   64

// Main tile config (R5-validated): 128x128, 4 waves (2x2), BK=64, LDS dbuf 64KB
#define BM 128
#define BN 128
#define BK 64
#define KSTEPS 8             // D_DIM / BK
#define ROWT 8               // LMAX / BM
#define COLT 4               // K_DIM / BN
#define NWG  (B_C * ROWT * COLT)   // 2048, divisible by 8 XCDs

#define WS_NEED ((size_t)B_C * D_DIM * K_DIM * 2)   // 32 MiB bf16 W^T slices

typedef __attribute__((ext_vector_type(8))) short bf16x8;
typedef __attribute__((ext_vector_type(4))) float f32x4;

__device__ __forceinline__ short f2bf(float f) {
    union { __hip_bfloat16 h; short s; } u;
    u.h = __float2bfloat16(f);
    return u.s;
}

// R3/R5-validated zero-conflict swizzle for 128B rows (8 x 16B slots)
__device__ __forceinline__ int fS(int r) { return (r & 7) ^ ((r >> 2) & 7); }

// ---------------- pre-pass: W[index[b]] f32 [k][n] -> ws bf16 [b][n][k] ----
__global__ __launch_bounds__(256) void wconv_kernel(
    const int* __restrict__ index,
    const float* __restrict__ weight,
    short* __restrict__ wbf)
{
    __shared__ float tile[64][65];
    const int blk = blockIdx.x;        // b(6b) | nt(3b) | kt(3b)
    const int b  = blk >> 6;
    const int nt = (blk >> 3) & 7;
    const int kt = blk & 7;
    const int idxw = index[b];
    const float* W = weight + (size_t)idxw * D_DIM * K_DIM;

    const int tid = threadIdx.x;
    // read phase: 64 k-rows x 64 n (f32), coalesced
    {
        const int rr = tid >> 2;       // k-row in tile
        const int rq = tid & 3;        // 16 f32 at n-offset rq*16
        f32x4 v[4];
#pragma unroll
        for (int j = 0; j < 4; ++j)
            v[j] = *reinterpret_cast<const f32x4*>(
                &W[(size_t)(kt * 64 + rr) * K_DIM + nt * 64 + rq * 16 + 4 * j]);
#pragma unroll
        for (int j = 0; j < 4; ++j)
#pragma unroll
            for (int e = 0; e < 4; ++e)
                tile[rr][rq * 16 + 4 * j + e] = v[j][e];
    }
    __syncthreads();
    // write phase: 64 n-rows x 64 k (bf16), transposed out of LDS
    {
        const int wrow = tid >> 2;     // n-row in tile
        const int wq   = tid & 3;      // 16 k at k-offset wq*16
        bf16x8 o0, o1;
#pragma unroll
        for (int j = 0; j < 8; ++j) o0[j] = f2bf(tile[wq * 16 + j][wrow]);
#pragma unroll
        for (int j = 0; j < 8; ++j) o1[j] = f2bf(tile[wq * 16 + 8 + j][wrow]);
        short* dst = wbf + ((size_t)b << 18) +
                     (size_t)(nt * 64 + wrow) * D_DIM + kt * 64 + wq * 16;
        *reinterpret_cast<bf16x8*>(dst)     = o0;
        *reinterpret_cast<bf16x8*>(dst + 8) = o1;
    }
}

// ---------------- main kernel ----------------
template <bool WCONV>
__global__ __launch_bounds__(256) void jbmm_kernel(
    const int* __restrict__ offsets,
    const int* __restrict__ index,
    const float* __restrict__ jagged,
    const float* __restrict__ weight,
    const short* __restrict__ wbf,     // bf16 [b][n][k] (WCONV only)
    const float* __restrict__ bias,
    float* __restrict__ out)
{
    __shared__ short As[2][BM * BK];   // 16 KB each
    __shared__ short Bs[2][BN * BK];   // 16 KB each

    const int bidRaw = blockIdx.x;
    const int bid = (bidRaw & 7) * (NWG / 8) + (bidRaw >> 3);

    const int b   = bid / (ROWT * COLT);
    const int rt  = (bid / COLT) % ROWT;
    const int ct  = bid % COLT;

    const int start = offsets[b];
    const int end   = offsets[b + 1];
    const int m0    = start + rt * BM;
    if (m0 >= end) return;
    const int rows = (end - m0) < BM ? (end - m0) : BM;

    const int idxw = index[b];
    const float* W = weight + (size_t)idxw * D_DIM * K_DIM;
    const short* WT = wbf + ((size_t)b << 18);   // [n][k] bf16
    const int n0 = ct * BN;

    const int tid  = threadIdx.x;
    const int lane = tid & 63;
    const int wid  = tid >> 6;
    const int wr   = wid >> 1;
    const int wc   = wid & 1;
    const int lr   = lane & 15;
    const int lg   = lane >> 4;

    // staging maps
    const int arow  = tid >> 3;  // 0..31 (+32*i)
    const int acol8 = tid & 7;   // 8 consecutive f32
    // f32-W path (fallback)
    const int n4  = tid & 31;
    const int dq8 = tid >> 5;
    // bf16-W path: 2 threads per n-row, 32 bf16 each
    const int nrowB  = tid >> 1;  // 0..127
    const int khalfB = tid & 1;   // 0..1

    float bias_v[4];
#pragma unroll
    for (int ni = 0; ni < 4; ++ni)
        bias_v[ni] = bias[(size_t)idxw * K_DIM + n0 + wc * 64 + ni * 16 + lr];

    f32x4 acc[4][4];
#pragma unroll
    for (int mi = 0; mi < 4; ++mi)
#pragma unroll
        for (int ni = 0; ni < 4; ++ni)
            acc[mi][ni] = (f32x4){0.f, 0.f, 0.f, 0.f};

    f32x4 aR[8];
    f32x4 bRf[8];      // f32 path
    bf16x8 bRh[4];     // bf16 path

#define LOADA(k0_)                                                          \
    {                                                                       \
        _Pragma("unroll")                                                   \
        for (int i = 0; i < 4; ++i) {                                       \
            const int r = arow + 32 * i;                                    \
            f32x4 v0 = (f32x4){0.f,0.f,0.f,0.f};                            \
            f32x4 v1 = (f32x4){0.f,0.f,0.f,0.f};                            \
            if (r < rows) {                                                 \
                const float* p = &jagged[(size_t)(m0 + r) * D_DIM + (k0_) + acol8 * 8]; \
                v0 = *reinterpret_cast<const f32x4*>(p);                    \
                v1 = *reinterpret_cast<const f32x4*>(p + 4);                \
            }                                                               \
            aR[2 * i] = v0; aR[2 * i + 1] = v1;                             \
        }                                                                   \
    }

#define LOADB(k0_)                                                          \
    {                                                                       \
        if constexpr (WCONV) {                                              \
            const short* p = WT + (size_t)(n0 + nrowB) * D_DIM + (k0_) + khalfB * 32; \
            _Pragma("unroll")                                               \
            for (int j = 0; j < 4; ++j)                                     \
                bRh[j] = *reinterpret_cast<const bf16x8*>(p + 8 * j);       \
        } else {                                                            \
            _Pragma("unroll")                                               \
            for (int j = 0; j < 8; ++j)                                     \
                bRf[j] = *reinterpret_cast<const f32x4*>(                   \
                    &W[(size_t)((k0_) + dq8 * 8 + j) * K_DIM + n0 + n4 * 4]); \
        }                                                                   \
    }

#define CVTSTORE(c_)                                                        \
    {                                                                       \
        _Pragma("unroll")                                                   \
        for (int i = 0; i < 4; ++i) {                                       \
            const int r = arow + 32 * i;                                    \
            bf16x8 w8;                                                      \
            w8[0] = f2bf(aR[2*i][0]); w8[1] = f2bf(aR[2*i][1]);             \
            w8[2] = f2bf(aR[2*i][2]); w8[3] = f2bf(aR[2*i][3]);             \
            w8[4] = f2bf(aR[2*i+1][0]); w8[5] = f2bf(aR[2*i+1][1]);         \
            w8[6] = f2bf(aR[2*i+1][2]); w8[7] = f2bf(aR[2*i+1][3]);         \
            *reinterpret_cast<bf16x8*>(                                     \
                (char*)&As[c_][0] + r * 128 + ((acol8 ^ fS(r)) << 4)) = w8; \
        }                                                                   \
        if constexpr (WCONV) {                                              \
            _Pragma("unroll")                                               \
            for (int j = 0; j < 4; ++j) {                                   \
                const int sl = (khalfB * 4 + j) ^ fS(nrowB);                \
                *reinterpret_cast<bf16x8*>(                                 \
                    (char*)&Bs[c_][0] + nrowB * 128 + (sl << 4)) = bRh[j];  \
            }                                                               \
        } else {                                                            \
            _Pragma("unroll")                                               \
            for (int np = 0; np < 4; ++np) {                                \
                const int row = n4 * 4 + np;                                \
                bf16x8 w8;                                                  \
                w8[0] = f2bf(bRf[0][np]); w8[1] = f2bf(bRf[1][np]);         \
                w8[2] = f2bf(bRf[2][np]); w8[3] = f2bf(bRf[3][np]);         \
                w8[4] = f2bf(bRf[4][np]); w8[5] = f2bf(bRf[5][np]);         \
                w8[6] = f2bf(bRf[6][np]); w8[7] = f2bf(bRf[7][np]);         \
                *reinterpret_cast<bf16x8*>(                                 \
                    (char*)&Bs[c_][0] + row * 128 + ((dq8 ^ fS(row)) << 4)) = w8; \
            }                                                               \
        }                                                                   \
    }

#define COMPUTE(c_)                                                         \
    {                                                                       \
        __builtin_amdgcn_s_setprio(1);                                      \
        _Pragma("unroll")                                                   \
        for (int kh = 0; kh < 2; ++kh) {                                    \
            bf16x8 af[4], bfr[4];                                           \
            _Pragma("unroll")                                               \
            for (int mi = 0; mi < 4; ++mi) {                                \
                const int row = wr * 64 + mi * 16 + lr;                     \
                af[mi] = *reinterpret_cast<bf16x8*>(                        \
                    (char*)&As[c_][0] + row * 128 + (((kh * 4 + lg) ^ fS(row)) << 4)); \
            }                                                               \
            _Pragma("unroll")                                               \
            for (int ni = 0; ni < 4; ++ni) {                                \
                const int row = wc * 64 + ni * 16 + lr;                     \
                bfr[ni] = *reinterpret_cast<bf16x8*>(                       \
                    (char*)&Bs[c_][0] + row * 128 + (((kh * 4 + lg) ^ fS(row)) << 4)); \
            }                                                               \
            _Pragma("unroll")                                               \
            for (int mi = 0; mi < 4; ++mi)                                  \
                _Pragma("unroll")                                           \
                for (int ni = 0; ni < 4; ++ni)                              \
                    acc[mi][ni] = __builtin_amdgcn_mfma_f32_16x16x32_bf16(  \
                        af[mi], bfr[ni], acc[mi][ni], 0, 0, 0);             \
        }                                                                   \
        __builtin_amdgcn_s_setprio(0);                                      \
    }

#define BARRIER_LDS()                                                       \
    {                                                                       \
        asm volatile("s_waitcnt lgkmcnt(0)" ::: "memory");                  \
        __builtin_amdgcn_s_barrier();                                       \
        asm volatile("" ::: "memory");                                      \
    }

    LOADA(0); LOADB(0);
    CVTSTORE(0);
    BARRIER_LDS();

#pragma unroll
    for (int t = 0; t < KSTEPS; ++t) {
        if (t + 1 < KSTEPS) {
            const int kn = (t + 1) * BK;
            LOADA(kn); LOADB(kn);      // in flight across COMPUTE, survives barrier
        }
        COMPUTE(t & 1);
        if (t + 1 < KSTEPS) {
            CVTSTORE((t + 1) & 1);
            BARRIER_LDS();
        }
    }

#pragma unroll
    for (int mi = 0; mi < 4; ++mi) {
        const int rloc = wr * 64 + mi * 16 + lg * 4;
#pragma unroll
        for (int r = 0; r < 4; ++r) {
            const int rr = rloc + r;
            if (rr < rows) {
#pragma unroll
                for (int ni = 0; ni < 4; ++ni) {
                    out[(size_t)(m0 + rr) * K_DIM + n0 + wc * 64 + ni * 16 + lr] =
                        acc[mi][ni][r] + bias_v[ni];
                }
            }
        }
    }
}

extern "C" void kernel_launch(void* const* d_in, const int* in_sizes, int n_in,
                              void* d_out, int out_size, void* d_ws, size_t ws_size,
                              hipStream_t stream) {
    const int*   offsets = (const int*)d_in[1];
    const int*   index   = (const int*)d_in[2];
    const float* jagged  = (const float*)d_in[3];
    const float* weight  = (const float*)d_in[4];
    const float* bias    = (const float*)d_in[5];
    float*       out     = (float*)d_out;
    short*       wbf     = (short*)d_ws;

    if (ws_size >= WS_NEED) {
        hipLaunchKernelGGL(wconv_kernel, dim3(B_C * 64), dim3(256), 0, stream,
                           index, weight, wbf);
        hipLaunchKernelGGL((jbmm_kernel<true>), dim3(NWG), dim3(256), 0, stream,
                           offsets, index, jagged, weight, wbf, bias, out);
    } else {
        hipLaunchKernelGGL((jbmm_kernel<false>), dim3(NWG), dim3(256), 0, stream,
                           offsets, index, jagged, weight, wbf, bias, out);
    }
}